// Round 3
// baseline (277.671 us; speedup 1.0000x reference)
//
#include <hip/hip_runtime.h>
#include <math.h>

// FIRE bias, single fused kernel — ROUND 3 = MEASUREMENT ROUND.
// Kernel body identical to Round 2. The launcher enqueues fire_fused TWICE
// (idempotent: identical bytes written both times) so that
//   dur_us(R3) - dur_us(R2)  =  true duration X of one fire_fused dispatch,
// which rocprof's top-5 cannot show us (all 5 slots are ~120us harness fills).
// Decision tree: X<=50us -> kernel is write-roofline-bound, declare done.
//                X>=75us -> 2x ownable headroom in the store path, dig there.

#define SDIM 2048
#define WDIM 32
#define HDIM 12
#define NK 33            // intervals = WDIM + 1
#define EPSF 1e-6f
#define LOGB 1.0f

typedef float f32x4 __attribute__((ext_vector_type(4)));

__global__ __launch_bounds__(512) void fire_fused(
    const float* __restrict__ w1, const float* __restrict__ b1,
    const float* __restrict__ w2, const float* __restrict__ b2,
    const float* __restrict__ cptr, const float* __restrict__ lmptr,
    const float* __restrict__ ilptr, float* __restrict__ out)
{
    __shared__ __align__(16) float sLR[SDIM];     // lr[d] table, 8 KB
    __shared__ __align__(16) float sAB[NK * 24];  // k-major (alpha',beta) pairs
    __shared__ float sTp[64];                     // thresholds * ln_i, +INF pad
    __shared__ float traw[WDIM], w1s[WDIM], b1s[WDIM];
    __shared__ int   rnk[WDIM], neg[WDIM];
    __shared__ float sLn[2];                      // { ln_i, 1/ln_i }

    const int tid = threadIdx.x;
    const int i   = blockIdx.x;
    const float c = cptr[0];

    // ---- per-block table build (overlapped across 2048 blocks; ~free) ----
    {   // lr table: 4 logf per thread (bit-identical to reference math)
        const int d0 = tid * 4;
        #pragma unroll
        for (int e = 0; e < 4; ++e) {
            const float d = (float)(d0 + e);
            sLR[d0 + e] = logf(fmaf(d + EPSF, c, LOGB + EPSF));
        }
    }
    if (tid == 0) {
        const float thr = fabsf(lmptr[0] * ilptr[0]);
        const float pn  = fmaxf((float)i, thr) + EPSF;
        const float ln  = logf(fabsf(c * pn) + LOGB + EPSF);  // > 0 always
        sLn[0] = ln; sLn[1] = 1.0f / ln;
    }
    if (tid < WDIM) {
        const float a = w1[tid], b = b1[tid];
        w1s[tid] = a; b1s[tid] = b;
        float t; int isneg;
        if (a > 0.f)      { t = -b / a; isneg = 0; }
        else if (a < 0.f) { t = -b / a; isneg = 1; }
        else {
            // w1==0: relu(b1) constant. "always active" (t=-inf) if b1>0,
            // "never active" (t=+inf) otherwise; treat as positive slope.
            t = (b > 0.f) ? -INFINITY : INFINITY; isneg = 0;
        }
        traw[tid] = t; neg[tid] = isneg;
    }
    __syncthreads();

    if (tid < WDIM) {
        // rank via O(W^2) counting sort (ties broken by index)
        const float t = traw[tid];
        int r = 0;
        for (int v = 0; v < WDIM; ++v) {
            const float tv = traw[v];
            if (tv < t || (tv == t && v < tid)) r++;
        }
        rnk[tid] = r;
        // search happens in lr-space: compare lr vs t*ln_i (ln_i > 0 so the
        // comparison direction is preserved; any ulp-level k-flip lands at a
        // breakpoint of a CONTINUOUS piecewise-linear function -> ulp output)
        sTp[r] = t * sLn[0];          // INF * ln_i = INF, ok
    } else if (tid < 64) {
        sTp[tid] = INFINITY;          // pad for 6-step binary search
    }
    __syncthreads();

    // interval k: t_sorted[k-1] <= nd < t_sorted[k]  (k in [0,32])
    // positive-slope w active iff rank(w) < k; negative-slope iff rank(w) >= k
    if (tid < NK * HDIM) {
        const int k = tid / HDIM;
        const int h = tid % HDIM;
        float a = 0.f, bb = 0.f;
        for (int w = 0; w < WDIM; ++w) {
            const bool active = neg[w] ? (rnk[w] >= k) : (rnk[w] < k);
            if (active) {
                const float w2v = w2[h * WDIM + w];
                a  += w2v * w1s[w];
                bb += w2v * b1s[w];
            }
        }
        bb += b2[h];
        sAB[k * 24 + h * 2 + 0] = a * sLn[1];   // fold inv_ln into alpha
        sAB[k * 24 + h * 2 + 1] = bb;
    }
    __syncthreads();

    // ---- hot loop: one row i, 512 threads x 4 elements ----
    const int j0 = tid * 4;
    float lrv[4];
    int   kk[4];
    #pragma unroll
    for (int e = 0; e < 4; ++e) {
        const int j = j0 + e;
        int dd = i - j; if (dd < 0) dd = -dd;
        const float x = sLR[dd];
        // branchless lower_bound over 64-padded scaled thresholds -> k in [0,32]
        int k = 0;
        if (x > sTp[k + 31]) k += 32;
        if (x > sTp[k + 15]) k += 16;
        if (x > sTp[k + 7])  k += 8;
        if (x > sTp[k + 3])  k += 4;
        if (x > sTp[k + 1])  k += 2;
        if (x > sTp[k])      k += 1;
        kk[e] = k;
        lrv[e] = x;
    }

    const size_t base = (size_t)i * SDIM + (size_t)j0;
    #pragma unroll
    for (int hp = 0; hp < 6; ++hp) {            // 2 heads per iteration
        f32x4 va, vb;
        #pragma unroll
        for (int e = 0; e < 4; ++e) {
            // 16B-aligned: byte off = kk*96 + hp*16
            const f32x4 ab = *(const f32x4*)&sAB[kk[e] * 24 + hp * 4];
            va[e] = fmaf(ab.x, lrv[e], ab.y);
            vb[e] = fmaf(ab.z, lrv[e], ab.w);
        }
        *(f32x4*)(out + (size_t)(2 * hp)     * SDIM * SDIM + base) = va;
        *(f32x4*)(out + (size_t)(2 * hp + 1) * SDIM * SDIM + base) = vb;
    }
}

extern "C" void kernel_launch(void* const* d_in, const int* in_sizes, int n_in,
                              void* d_out, int out_size, void* d_ws, size_t ws_size,
                              hipStream_t stream)
{
    // inputs: 0:x (unused, shape only), 1:w1[32], 2:b1[32], 3:w2[12,32],
    //         4:b2[12], 5:c, 6:L_multiplier, 7:init_L
    const float* w1 = (const float*)d_in[1];
    const float* b1 = (const float*)d_in[2];
    const float* w2 = (const float*)d_in[3];
    const float* b2 = (const float*)d_in[4];
    const float* c  = (const float*)d_in[5];
    const float* lm = (const float*)d_in[6];
    const float* il = (const float*)d_in[7];
    float* out = (float*)d_out;

    // MEASUREMENT: two identical, idempotent launches. dur_us(R3)-dur_us(R2)
    // = one fire_fused duration. Revert to single launch next round.
    fire_fused<<<SDIM, 512, 0, stream>>>(w1, b1, w2, b2, c, lm, il, out);
    fire_fused<<<SDIM, 512, 0, stream>>>(w1, b1, w2, b2, c, lm, il, out);
}

// Round 4
// 213.445 us; speedup vs baseline: 1.3009x; 1.3009x over previous
//
#include <hip/hip_runtime.h>
#include <math.h>

// FIRE bias, single fused kernel — ROUND 4: barrier-free multi-row streaming.
//
//   out[h,i,j] = MLP(nd(i,j)),  nd = lr(|i-j|) / ln(i),
//   lr(d) = log((d+eps)*c + 1 + eps),  ln(i) = log(|c*(max(i,thr)+eps)| + 1 + eps)
//   MLP: relu(nd*w1 + b1) dot w2 + b2   (1 -> 32 -> 12), piecewise-linear in nd
//   with <=32 breakpoints -> per-interval (alpha,beta) per head.
//
// R3 measurement (double-launch): one dispatch = ~51us, vs ~31us write-roofline
// for the 201MB output at the fill's demonstrated 6.7 TB/s. Theory: 2048
// blocks x full prologue (8KB table + W^2 sort + AB build + 3 barriers) =
// 2048 store-pipe drains; fill proves BW needs uninterrupted streams, not
// occupancy (it hits 84% peak at ~3 waves/CU).
//
// This round: 512 blocks x 4 rows. Prologue ONCE per block; the row loop has
// ZERO barriers — thresholds and (alpha,beta) stay in nd-space (read-only
// after prologue), each thread computes its own ivl=1/ln(i) per row and
// searches on nd = lr[d]*ivl (one extra mult/element, proven free in R1).

#define SDIM 2048
#define WDIM 32
#define HDIM 12
#define NK 33            // intervals = WDIM + 1
#define NROWS 4          // rows per block
#define EPSF 1e-6f
#define LOGB 1.0f

typedef float f32x4 __attribute__((ext_vector_type(4)));

__global__ __launch_bounds__(512) void fire_fused(
    const float* __restrict__ w1, const float* __restrict__ b1,
    const float* __restrict__ w2, const float* __restrict__ b2,
    const float* __restrict__ cptr, const float* __restrict__ lmptr,
    const float* __restrict__ ilptr, float* __restrict__ out)
{
    __shared__ __align__(16) float sLR[SDIM];     // lr[d] table, 8 KB
    __shared__ __align__(16) float sAB[NK * 24];  // k-major (alpha,beta), nd-space
    __shared__ float sT[64];                      // sorted thresholds, +INF pad
    __shared__ float traw[WDIM], w1s[WDIM], b1s[WDIM];
    __shared__ int   rnk[WDIM], neg[WDIM];

    const int tid = threadIdx.x;
    const float c = cptr[0];

    // ---- prologue: build tables ONCE per block ----
    {   // lr table: 4 logf per thread (bit-identical to reference math)
        const int d0 = tid * 4;
        #pragma unroll
        for (int e = 0; e < 4; ++e) {
            const float d = (float)(d0 + e);
            sLR[d0 + e] = logf(fmaf(d + EPSF, c, LOGB + EPSF));
        }
    }
    if (tid < WDIM) {
        const float a = w1[tid], b = b1[tid];
        w1s[tid] = a; b1s[tid] = b;
        float t; int isneg;
        if (a > 0.f)      { t = -b / a; isneg = 0; }
        else if (a < 0.f) { t = -b / a; isneg = 1; }
        else {
            // w1==0: relu(b1) constant. "always active" (t=-inf) if b1>0,
            // "never active" (t=+inf) otherwise; treat as positive slope.
            t = (b > 0.f) ? -INFINITY : INFINITY; isneg = 0;
        }
        traw[tid] = t; neg[tid] = isneg;
    }
    __syncthreads();

    if (tid < WDIM) {
        // rank via O(W^2) counting sort (ties broken by index)
        const float t = traw[tid];
        int r = 0;
        for (int v = 0; v < WDIM; ++v) {
            const float tv = traw[v];
            if (tv < t || (tv == t && v < tid)) r++;
        }
        rnk[tid] = r;
        sT[r] = t;                    // nd-space, unscaled
    } else if (tid < 64) {
        sT[tid] = INFINITY;           // pad for 6-step binary search
    }
    __syncthreads();

    // interval k: t_sorted[k-1] <= nd < t_sorted[k]  (k in [0,32])
    // positive-slope w active iff rank(w) < k; negative-slope iff rank(w) >= k
    if (tid < NK * HDIM) {
        const int k = tid / HDIM;
        const int h = tid % HDIM;
        float a = 0.f, bb = 0.f;
        for (int w = 0; w < WDIM; ++w) {
            const bool active = neg[w] ? (rnk[w] >= k) : (rnk[w] < k);
            if (active) {
                const float w2v = w2[h * WDIM + w];
                a  += w2v * w1s[w];
                bb += w2v * b1s[w];
            }
        }
        bb += b2[h];
        sAB[k * 24 + h * 2 + 0] = a;   // nd-space (unscaled)
        sAB[k * 24 + h * 2 + 1] = bb;
    }
    __syncthreads();
    // ---- all shared state is read-only from here: NO barriers below ----

    const float thr = fabsf(lmptr[0] * ilptr[0]);
    const int   i0  = (int)blockIdx.x * NROWS;
    const int   j0  = tid * 4;

    for (int r = 0; r < NROWS; ++r) {
        const int i = i0 + r;
        // per-row scalar (same in all lanes; ~free per R1)
        const float pn  = fmaxf((float)i, thr) + EPSF;
        const float ivl = 1.0f / logf(fabsf(c * pn) + LOGB + EPSF);

        float ndv[4];
        int   kk[4];
        #pragma unroll
        for (int e = 0; e < 4; ++e) {
            const int j = j0 + e;
            int dd = i - j; if (dd < 0) dd = -dd;
            const float x = sLR[dd] * ivl;    // nd-space
            // branchless lower_bound over 64-padded thresholds -> k in [0,32]
            int k = 0;
            if (x > sT[k + 31]) k += 32;
            if (x > sT[k + 15]) k += 16;
            if (x > sT[k + 7])  k += 8;
            if (x > sT[k + 3])  k += 4;
            if (x > sT[k + 1])  k += 2;
            if (x > sT[k])      k += 1;
            kk[e] = k;
            ndv[e] = x;
        }

        const size_t base = (size_t)i * SDIM + (size_t)j0;
        #pragma unroll
        for (int hp = 0; hp < 6; ++hp) {      // 2 heads per iteration
            f32x4 va, vb;
            #pragma unroll
            for (int e = 0; e < 4; ++e) {
                // 16B-aligned: byte off = kk*96 + hp*16
                const f32x4 ab = *(const f32x4*)&sAB[kk[e] * 24 + hp * 4];
                va[e] = fmaf(ab.x, ndv[e], ab.y);
                vb[e] = fmaf(ab.z, ndv[e], ab.w);
            }
            *(f32x4*)(out + (size_t)(2 * hp)     * SDIM * SDIM + base) = va;
            *(f32x4*)(out + (size_t)(2 * hp + 1) * SDIM * SDIM + base) = vb;
        }
    }
}

extern "C" void kernel_launch(void* const* d_in, const int* in_sizes, int n_in,
                              void* d_out, int out_size, void* d_ws, size_t ws_size,
                              hipStream_t stream)
{
    // inputs: 0:x (unused, shape only), 1:w1[32], 2:b1[32], 3:w2[12,32],
    //         4:b2[12], 5:c, 6:L_multiplier, 7:init_L
    const float* w1 = (const float*)d_in[1];
    const float* b1 = (const float*)d_in[2];
    const float* w2 = (const float*)d_in[3];
    const float* b2 = (const float*)d_in[4];
    const float* c  = (const float*)d_in[5];
    const float* lm = (const float*)d_in[6];
    const float* il = (const float*)d_in[7];
    float* out = (float*)d_out;

    fire_fused<<<SDIM / NROWS, 512, 0, stream>>>(w1, b1, w2, b2, c, lm, il, out);
}